// Round 2
// baseline (2480.671 us; speedup 1.0000x reference)
//
#include <hip/hip_runtime.h>
#include <stdint.h>

// ---------------- problem constants ----------------
#define BB 2
#define HH 32
#define NBH 64          // BB*HH
#define S 8192
#define DD 128
#define SP 7936         // S - KEEP
#define MC 256          // MEM_COMPRESS
#define KEEP 256
#define LOC 64
#define KTOP 192        // KEEP - LOC
#define N1 8128         // S - LOC (top-k domain)
#define OC0 512
#define IC0 256
#define KK0 768         // 3*IC0 (im2col K)
#define OC1 256
#define IC1 512
#define KK1 1536
#define KEYS_TOTAL ((size_t)NBH * 512 * DD)   // 4,194,304

typedef unsigned short u16;
typedef __attribute__((ext_vector_type(2))) unsigned short us2;
typedef __attribute__((ext_vector_type(4))) unsigned short us4;
typedef __attribute__((ext_vector_type(8))) unsigned short us8;
typedef __attribute__((ext_vector_type(8))) short bfrag;   // 8 bf16 (4 VGPRs) MFMA input
typedef __attribute__((ext_vector_type(4))) float ffrag;   // 4 fp32 MFMA acc

__device__ __forceinline__ u16 f2bf(float x) {          // RNE fp32->bf16
  uint32_t u = __float_as_uint(x);
  return (u16)((u + 0x7FFFu + ((u >> 16) & 1u)) >> 16);
}
__device__ __forceinline__ float bf2f(u16 h) {
  return __uint_as_float(((uint32_t)h) << 16);
}

// async global->LDS, 16 B per lane. LDS dest is wave-uniform base + lane*16;
// global source is per-lane.  [m97 recipe: width=16 -> global_load_lds_dwordx4]
__device__ __forceinline__ void gl_lds16(const u16* g, u16* l) {
  __builtin_amdgcn_global_load_lds(
      (const __attribute__((address_space(1))) void*)g,
      (__attribute__((address_space(3))) void*)l,
      16, 0, 0);
}

// ================= selection (exact top-k, tie -> lower index) =================
// Also zero-inits the per-(slot,row) softmax-denominator buffer for this chunk.
__global__ __launch_bounds__(256) void sel_kernel(
    const float* __restrict__ scores, int bh0,
    int* __restrict__ non_pos_g, int* __restrict__ hh_pos_g, int* __restrict__ rpos_g,
    float* __restrict__ sums_g)
{
  __shared__ uint32_t keys[N1];        // transformed order-preserving bits, 31.75 KB
  __shared__ u16 nonpos_l[SP];         // 15.5 KB
  __shared__ uint32_t hist[256];
  __shared__ int scanb[256];
  __shared__ uint32_t s_pref, s_pmask;
  __shared__ int s_krem;

  const int slot = blockIdx.x;
  const int bh = bh0 + slot;
  const int tid = threadIdx.x;
  const float* row = scores + (size_t)bh * S;

  sums_g[slot * MC + tid] = 0.0f;      // MC == 256 == blockDim

  for (int i = tid; i < N1; i += 256) {
    uint32_t u = __float_as_uint(row[i]);
    keys[i] = (u >> 31) ? ~u : (u | 0x80000000u);   // monotone map, descending order
  }
  __syncthreads();

  // ---- stage 1: 192-th largest over [0, N1)
  if (tid == 0) { s_pref = 0; s_pmask = 0; s_krem = KTOP; }
  __syncthreads();
  for (int shift = 24; shift >= 0; shift -= 8) {
    hist[tid] = 0; __syncthreads();
    uint32_t pm = s_pmask, pf = s_pref;
    for (int i = tid; i < N1; i += 256) {
      uint32_t u = keys[i];
      if ((u & pm) == pf) atomicAdd(&hist[(u >> shift) & 255u], 1u);
    }
    __syncthreads();
    if (tid == 0) {
      int krem = s_krem, c = 0, chosen = 0;
      for (int b = 255; b >= 0; --b) {
        int h = (int)hist[b];
        if (krem <= c + h) { chosen = b; krem -= c; break; }
        c += h;
      }
      s_pref |= ((uint32_t)chosen) << shift;
      s_pmask |= 255u << shift;
      s_krem = krem;
    }
    __syncthreads();
  }
  const uint32_t T1 = s_pref;
  const int need1 = s_krem;          // #elements == T1 to take (ascending index)

  // blocked ownership: 32 indices per thread over [0, S)
  const int base = tid * 32;
  int eqc = 0;
  for (int j = 0; j < 32; ++j) { int i = base + j; if (i < N1 && keys[i] == T1) ++eqc; }
  __syncthreads(); scanb[tid] = eqc; __syncthreads();
  if (tid == 0) { int run = 0; for (int t = 0; t < 256; ++t) { int v = scanb[t]; scanb[t] = run; run += v; } }
  __syncthreads();
  const int eqb = scanb[tid];

  int mcnt = 0;
  { int er = eqb;
    for (int j = 0; j < 32; ++j) {
      int i = base + j; bool m;
      if (i >= N1) m = true;
      else { uint32_t u = keys[i];
        if (u > T1) m = true; else if (u == T1) { m = (er < need1); ++er; } else m = false; }
      if (m) ++mcnt;
    } }
  __syncthreads(); scanb[tid] = mcnt; __syncthreads();
  if (tid == 0) { int run = 0; for (int t = 0; t < 256; ++t) { int v = scanb[t]; scanb[t] = run; run += v; } }
  __syncthreads();
  { int mo = scanb[tid];
    int no = base - mo;              // unmasked-before-base
    int er = eqb;
    for (int j = 0; j < 32; ++j) {
      int i = base + j; bool m;
      if (i >= N1) m = true;
      else { uint32_t u = keys[i];
        if (u > T1) m = true; else if (u == T1) { m = (er < need1); ++er; } else m = false; }
      if (m) { hh_pos_g[slot * KEEP + mo] = i; ++mo; }
      else   { nonpos_l[no] = (u16)i; non_pos_g[(size_t)slot * SP + no] = i; ++no; }
    } }
  __syncthreads();

  // ---- stage 2: 256-th largest over non_scores (7936), same tie rule
  if (tid == 0) { s_pref = 0; s_pmask = 0; s_krem = MC; }
  __syncthreads();
  for (int shift = 24; shift >= 0; shift -= 8) {
    hist[tid] = 0; __syncthreads();
    uint32_t pm = s_pmask, pf = s_pref;
    for (int i = tid; i < SP; i += 256) {
      uint32_t u = keys[nonpos_l[i]];
      if ((u & pm) == pf) atomicAdd(&hist[(u >> shift) & 255u], 1u);
    }
    __syncthreads();
    if (tid == 0) {
      int krem = s_krem, c = 0, chosen = 0;
      for (int b = 255; b >= 0; --b) {
        int h = (int)hist[b];
        if (krem <= c + h) { chosen = b; krem -= c; break; }
        c += h;
      }
      s_pref |= ((uint32_t)chosen) << shift;
      s_pmask |= 255u << shift;
      s_krem = krem;
    }
    __syncthreads();
  }
  const uint32_t T2 = s_pref;
  const int need2 = s_krem;
  const int b2 = tid * 31;           // 256*31 == 7936 exactly
  int eqc2 = 0;
  for (int j = 0; j < 31; ++j) { if (keys[nonpos_l[b2 + j]] == T2) ++eqc2; }
  __syncthreads(); scanb[tid] = eqc2; __syncthreads();
  if (tid == 0) { int run = 0; for (int t = 0; t < 256; ++t) { int v = scanb[t]; scanb[t] = run; run += v; } }
  __syncthreads();
  const int eqb2 = scanb[tid];
  int sc = 0;
  { int er = eqb2;
    for (int j = 0; j < 31; ++j) {
      uint32_t u = keys[nonpos_l[b2 + j]]; bool sel;
      if (u > T2) sel = true; else if (u == T2) { sel = (er < need2); ++er; } else sel = false;
      if (sel) ++sc;
    } }
  __syncthreads(); scanb[tid] = sc; __syncthreads();
  if (tid == 0) { int run = 0; for (int t = 0; t < 256; ++t) { int v = scanb[t]; scanb[t] = run; run += v; } }
  __syncthreads();
  { int so = scanb[tid];
    int er = eqb2;
    for (int j = 0; j < 31; ++j) {
      int i = b2 + j; uint32_t u = keys[nonpos_l[i]]; bool sel;
      if (u > T2) sel = true; else if (u == T2) { sel = (er < need2); ++er; } else sel = false;
      if (sel) { rpos_g[slot * MC + so] = (int)nonpos_l[i]; ++so; }   // ORIGINAL position
    } }
}

// ================= gather non-positions into bf16 X (time-major + d-major) ======
__global__ __launch_bounds__(256) void gather_kernel(
    const float* __restrict__ pk, const float* __restrict__ pv,
    const int* __restrict__ non_pos, u16* __restrict__ Xtm_all,
    u16* __restrict__ Xdm_all, u16* __restrict__ Y0_all, int bh0)
{
  __shared__ u16 lt[256][66];        // [ch][t_local], +2 pad vs bank conflicts
  const int slot = blockIdx.y, tile = blockIdx.x;
  const int bh = bh0 + slot;
  const int tid = threadIdx.x, lane = tid & 63, q = tid >> 6;
  const int t0 = tile * 64;
  u16* Xtm = Xtm_all + (size_t)slot * (SP + 2) * 256 + 256;   // logical row 0
  const int* np = non_pos + (size_t)slot * SP;

  for (int r = q; r < 64; r += 4) {
    const int t = t0 + r;
    const int pos = np[t];
    float2 kk = ((const float2*)(pk + ((size_t)bh * S + pos) * DD))[lane];
    float2 vv = ((const float2*)(pv + ((size_t)bh * S + pos) * DD))[lane];
    u16 k0 = f2bf(kk.x), k1 = f2bf(kk.y), v0 = f2bf(vv.x), v1 = f2bf(vv.y);
    us2 tk = {k0, k1}; us2 tv = {v0, v1};
    *(us2*)&Xtm[(size_t)t * 256 + lane * 2] = tk;
    *(us2*)&Xtm[(size_t)t * 256 + 128 + lane * 2] = tv;
    lt[lane * 2][r] = k0; lt[lane * 2 + 1][r] = k1;
    lt[128 + lane * 2][r] = v0; lt[128 + lane * 2 + 1][r] = v1;
  }
  // zero pad rows (conv tap t=-1 / t=SP), Y0 pads too
  if (tile == 0) {
    Xtm[-256 + tid] = 0;
    u16* y0 = Y0_all + (size_t)slot * (SP + 2) * 512;
    y0[tid] = 0; y0[tid + 256] = 0;
  } else if (tile == 123) {
    Xtm[(size_t)SP * 256 + tid] = 0;
    u16* y0 = Y0_all + (size_t)slot * (SP + 2) * 512 + (size_t)(SP + 1) * 512;
    y0[tid] = 0; y0[tid + 256] = 0;
  }
  __syncthreads();
  // X_dm rows (d-major, for weighting-GEMM B^T) — coalesced: 16 consecutive
  // lanes cover one row's 128 B (uint2 = 4 bf16 each) -> 4x128B tx per wave-store.
  u16* Xdm = Xdm_all + (size_t)slot * 256 * SP;
  for (int idx = tid; idx < 4096; idx += 256) {
    const int r = idx >> 4, j = idx & 15;
    uint2 v = *(const uint2*)&lt[r][j * 4];
    *(uint2*)(Xdm + (size_t)r * SP + t0 + j * 4) = v;
  }
}

// ================= heavy-hitter gather straight to output (fp32, exact) ========
__global__ __launch_bounds__(256) void hhgather_kernel(
    const float* __restrict__ pk, const float* __restrict__ pv,
    const int* __restrict__ hh_pos, float* __restrict__ out, int bh0)
{
  const int slot = blockIdx.y, bh = bh0 + slot;
  const int tid = threadIdx.x, lane = tid & 63, q = tid >> 6;
  const int r0 = blockIdx.x * 16;
  const int* hp = hh_pos + slot * KEEP;
  for (int r = r0 + q; r < r0 + 16; r += 4) {
    const int pos = hp[r];
    float2 kk = ((const float2*)(pk + ((size_t)bh * S + pos) * DD))[lane];
    float2 vv = ((const float2*)(pv + ((size_t)bh * S + pos) * DD))[lane];
    ((float2*)(out + ((size_t)bh * 512 + r) * DD))[lane] = kk;
    ((float2*)(out + KEYS_TOTAL + ((size_t)bh * 512 + r) * DD))[lane] = vv;
  }
}

// ================= weight prepack (im2col m-major, bf16) ========================
__global__ __launch_bounds__(256) void prepack_kernel(
    const float* __restrict__ w0, const float* __restrict__ w1,
    u16* __restrict__ A0, u16* __restrict__ A1)
{
  const int idx = blockIdx.x * 256 + threadIdx.x;
  if (idx < OC0 * KK0) {
    int oc = idx / KK0, r = idx % KK0, tau = r / IC0, ic = r % IC0;
    A0[idx] = f2bf(w0[(oc * IC0 + ic) * 3 + tau]);
  }
  if (idx < OC1 * KK1) {
    int oc = idx / KK1, r = idx % KK1, tau = r / IC1, ic = r % IC1;
    A1[idx] = f2bf(w1[(oc * IC1 + ic) * 3 + tau]);
  }
}

// ================= conv-as-GEMM (im2col via shifted time-major B) ===============
// C[oc][t] = sum_tau sum_ic W[oc][tau*TAUCH+ic] * Bsrc[t+tau-1][ic], then +bias, silu.
// Staging: async global_load_lds width=16, DOUBLE-BUFFERED (T3 minimum 2-phase):
// per K-step issue next-step loads first, then ds_read+MFMA current, then ONE
// __syncthreads (its implicit vmcnt(0) drain now sits AFTER the compute, so the
// load latency hides under ds_read+MFMA instead of being exposed per step).
// Grid is 1-D over (t,m) with m FASTEST + bijective XCD-chunk remap (m204) so
// the m-tiles sharing a B panel land on the same XCD's L2.
// OUTMODE 0: store silu(x) time-major (Y0, pad rows at -1/SP)
// OUTMODE 1: store p = exp(silu(x)) m-major (unnormalized softmax numerator)
//            and atomically accumulate per-row sums (softmax denominator).
template<int MTOT, int KTOT, int TAUCH, int OUTMODE>
__global__ __launch_bounds__(256) void conv_gemm_kernel(
    const u16* __restrict__ Apack, const u16* __restrict__ Bsrc_all,
    const float* __restrict__ bias, u16* __restrict__ out_all,
    float* __restrict__ sums_g)
{
  constexpr int MTILES = MTOT / 128;
  constexpr int NK = KTOT / 32;          // 24 (conv0) / 48 (conv1), even
  constexpr int NX = (SP / 128) * MTILES;
  constexpr int QX = NX / 8, RX = NX % 8;
  __shared__ u16 smem[128 * 136];    // staging dbuf 4x4096 u16; epilogue reuses whole
  __shared__ float rowsum[128];
  u16* A0l = smem;
  u16* A1l = smem + 4096;
  u16* B0l = smem + 8192;
  u16* B1l = smem + 12288;
  const int slot = blockIdx.y;
  // XCD-chunked bijective swizzle, m-fastest within chunk
  const int lin = blockIdx.x;
  const int xcd = lin & 7, pos = lin >> 3;
  const int widx = (xcd < RX ? xcd * (QX + 1) : RX * (QX + 1) + (xcd - RX) * QX) + pos;
  const int m0 = (widx % MTILES) * 128;
  const int t0 = (widx / MTILES) * 128;
  const int tid = threadIdx.x;
  const int lane = tid & 63, wave = tid >> 6;
  const int wm = (wave & 1) * 64, wn = (wave >> 1) * 64;
  const int r_fr = lane & 15, quad = lane >> 4;
  const u16* Bsrc = Bsrc_all + (size_t)slot * (size_t)(SP + 2) * TAUCH + TAUCH; // logical row 0

  ffrag acc[4][4];
  #pragma unroll
  for (int a = 0; a < 4; ++a)
    #pragma unroll
    for (int b = 0; b < 4; ++b) acc[a][b] = (ffrag)0.0f;

  // per-lane global sources for async staging: chunk c = 16 rows = 1024 B LDS;
  // lane l covers row c*16 + (l>>2), k-bytes [(l&3)*16, (l&3)*16+16).
  const int c0 = wave * 2;                       // this wave's first chunk
  const int lrow = lane >> 2, lcol = (lane & 3) * 8;
  const u16* gA0 = Apack + (size_t)(m0 + c0 * 16 + lrow) * KTOT + lcol;
  const u16* gA1 = gA0 + (size_t)16 * KTOT;
  const u16* gB0 = Bsrc + ((long)t0 + c0 * 16 + lrow - 1) * (long)TAUCH + lcol;
  const u16* gB1 = gB0 + (size_t)16 * TAUCH;
  u16* lA0 = A0l + c0 * 512; u16* lA1 = A1l + c0 * 512;  // wave-uniform LDS bases
  u16* lB0 = B0l + c0 * 512; u16* lB1 = B1l + c0 * 512;

  auto compute = [&](const u16* Asl, const u16* Bsl) {
    bfrag af[4], bf[4];
    #pragma unroll
    for (int mt = 0; mt < 4; ++mt)
      af[mt] = *(const bfrag*)&Asl[(wm + mt * 16 + r_fr) * 32 + quad * 8];
    #pragma unroll
    for (int nt = 0; nt < 4; ++nt)
      bf[nt] = *(const bfrag*)&Bsl[(wn + nt * 16 + r_fr) * 32 + quad * 8];
    #pragma unroll
    for (int mt = 0; mt < 4; ++mt)
      #pragma unroll
      for (int nt = 0; nt < 4; ++nt)
        acc[mt][nt] = __builtin_amdgcn_mfma_f32_16x16x32_bf16(af[mt], bf[nt], acc[mt][nt], 0, 0, 0);
  };

  // prologue: stage k-step 0 -> buf0, drain, barrier
  gl_lds16(gA0, lA0); gl_lds16(gA1, lA0 + 512);
  gl_lds16(gB0, lB0); gl_lds16(gB1, lB0 + 512);
  __syncthreads();

  for (int kp = 0; kp < NK / 2; ++kp) {
    {   // phase 0: stage k=2kp+1 -> buf1 (always valid: 2kp+1 <= NK-1), compute buf0
      const int ko = (2 * kp + 1) * 32;
      gl_lds16(gA0 + ko, lA1); gl_lds16(gA1 + ko, lA1 + 512);
      gl_lds16(gB0 + ko, lB1); gl_lds16(gB1 + ko, lB1 + 512);
    }
    compute(A0l, B0l);
    __syncthreads();              // implicit vmcnt(0): buf1 staged data visible
    if (2 * kp + 2 < NK) {        // phase 1: stage k=2kp+2 -> buf0, compute buf1
      const int ko = (2 * kp + 2) * 32;
      gl_lds16(gA0 + ko, lA0); gl_lds16(gA1 + ko, lA0 + 512);
      gl_lds16(gB0 + ko, lB0); gl_lds16(gB1 + ko, lB0 + 512);
    }
    compute(A1l, B1l);
    __syncthreads();
  }

  if constexpr (OUTMODE == 1) {
    if (tid < 128) rowsum[tid] = 0.0f;
    __syncthreads();
  }

  // epilogue: bias + silu (+exp for mode 1) -> bf16 -> LDS (for coalesced stores)
  #pragma unroll
  for (int mt = 0; mt < 4; ++mt) {
    float srow4[4] = {0.0f, 0.0f, 0.0f, 0.0f};
    #pragma unroll
    for (int nt = 0; nt < 4; ++nt) {
      const int n_l = wn + nt * 16 + r_fr;
      const int m_l = wm + mt * 16 + quad * 4;
      if constexpr (OUTMODE == 0) {
        u16 h4[4];
        #pragma unroll
        for (int r = 0; r < 4; ++r) {
          float x = acc[mt][nt][r] + bias[m0 + m_l + r];
          float y = x / (1.0f + __expf(-x));
          h4[r] = f2bf(y);
        }
        us4 p = {h4[0], h4[1], h4[2], h4[3]};
        *(us4*)&smem[n_l * 136 + m_l] = p;             // trans[n][m]
      } else {
        #pragma unroll
        for (int r = 0; r < 4; ++r) {
          float x = acc[mt][nt][r] + bias[m0 + m_l + r];
          float y = x / (1.0f + __expf(-x));
          float p = __expf(fminf(y, 60.0f));           // no-max-sub softmax numerator
          srow4[r] += p;
          smem[(m_l + r) * 136 + n_l] = f2bf(p);       // trans[m][n]
        }
      }
    }
    if constexpr (OUTMODE == 1) {
      #pragma unroll
      for (int r = 0; r < 4; ++r) {
        float s = srow4[r];
        s += __shfl_xor(s, 1, 64);
        s += __shfl_xor(s, 2, 64);
        s += __shfl_xor(s, 4, 64);
        s += __shfl_xor(s, 8, 64);
        if ((lane & 15) == 0)
          atomicAdd(&rowsum[wm + mt * 16 + quad * 4 + r], s);
      }
    }
  }
  __syncthreads();
  if constexpr (OUTMODE == 1) {
    if (tid < 128) atomicAdd(&sums_g[slot * MC + m0 + tid], rowsum[tid]);
  }
  const int rr = tid >> 1, half = tid & 1;
  if (OUTMODE == 0) {
    u16* orow = out_all + (size_t)slot * (size_t)(SP + 2) * MTOT + MTOT
              + (size_t)(t0 + rr) * MTOT + m0 + half * 64;
    const u16* srcr = &smem[rr * 136 + half * 64];
    #pragma unroll
    for (int j = 0; j < 8; ++j) *(us8*)(orow + j * 8) = *(const us8*)(srcr + j * 8);
  } else {
    u16* orow = out_all + (size_t)slot * (size_t)MC * SP
              + (size_t)(m0 + rr) * SP + t0 + half * 64;
    const u16* srcr = &smem[rr * 136 + half * 64];
    #pragma unroll
    for (int j = 0; j < 8; ++j) *(us8*)(orow + j * 8) = *(const us8*)(srcr + j * 8);
  }
}

// ================= weighting GEMM: C(256m x 256d) = P(256xSP) x non(SPx256) =====
// A = unnormalized p (bf16, m-major); B^T = Xdm (256 d-rows x SP).
// K split 4 ways into fp32 partials (normalization applied in combine).
// Staging: async global_load_lds width=16, double-buffered (same scheme as conv).
__global__ __launch_bounds__(256) void gemm3_kernel(
    const u16* __restrict__ Wmm_all, const u16* __restrict__ Xdm_all,
    float* __restrict__ part)
{
  __shared__ u16 smem[16384];          // 4 x 4096 u16 staging dbuf
  u16* A0l = smem;
  u16* A1l = smem + 4096;
  u16* B0l = smem + 8192;
  u16* B1l = smem + 12288;
  const int kc = blockIdx.x;            // 0..3
  const int tile = blockIdx.y;          // 0..3  (2m x 2n)
  const int slot = blockIdx.z;
  const int m0 = (tile >> 1) * 128, n0 = (tile & 1) * 128;
  const int tid = threadIdx.x;
  const int lane = tid & 63, wave = tid >> 6;
  const int wm = (wave & 1) * 64, wn = (wave >> 1) * 64;
  const int r_fr = lane & 15, quad = lane >> 4;
  const u16* A = Wmm_all + (size_t)slot * MC * SP;
  const u16* Bt = Xdm_all + (size_t)slot * 256 * SP;
  const int kbeg = kc * (SP / 4);
  constexpr int NK = (SP / 4) / 32;     // 62, even

  ffrag acc[4][4];
  #pragma unroll
  for (int a = 0; a < 4; ++a)
    #pragma unroll
    for (int b = 0; b < 4; ++b) acc[a][b] = (ffrag)0.0f;

  const int c0 = wave * 2;
  const int lrow = lane >> 2, lcol = (lane & 3) * 8;
  const u16* gA0 = A + (size_t)(m0 + c0 * 16 + lrow) * SP + kbeg + lcol;
  const u16* gA1 = gA0 + (size_t)16 * SP;
  const u16* gB0 = Bt + (size_t)(n0 + c0 * 16 + lrow) * SP + kbeg + lcol;
  const u16* gB1 = gB0 + (size_t)16 * SP;
  u16* lA0 = A0l + c0 * 512; u16* lA1 = A1l + c0 * 512;
  u16* lB0 = B0l + c0 * 512; u16* lB1 = B1l + c0 * 512;

  auto compute = [&](const u16* Asl, const u16* Bsl) {
    bfrag af[4], bf[4];
    #pragma unroll
    for (int mt = 0; mt < 4; ++mt)
      af[mt] = *(const bfrag*)&Asl[(wm + mt * 16 + r_fr) * 32 + quad * 8];
    #pragma unroll
    for (int nt = 0; nt < 4; ++nt)
      bf[nt] = *(const bfrag*)&Bsl[(wn + nt * 16 + r_fr) * 32 + quad * 8];
    #pragma unroll
    for (int mt = 0; mt < 4; ++mt)
      #pragma unroll
      for (int nt = 0; nt < 4; ++nt)
        acc[mt][nt] = __builtin_amdgcn_mfma_f32_16x16x32_bf16(af[mt], bf[nt], acc[mt][nt], 0, 0, 0);
  };

  gl_lds16(gA0, lA0); gl_lds16(gA1, lA0 + 512);
  gl_lds16(gB0, lB0); gl_lds16(gB1, lB0 + 512);
  __syncthreads();

  for (int kp = 0; kp < NK / 2; ++kp) {
    {
      const int ko = (2 * kp + 1) * 32;
      gl_lds16(gA0 + ko, lA1); gl_lds16(gA1 + ko, lA1 + 512);
      gl_lds16(gB0 + ko, lB1); gl_lds16(gB1 + ko, lB1 + 512);
    }
    compute(A0l, B0l);
    __syncthreads();
    if (2 * kp + 2 < NK) {
      const int ko = (2 * kp + 2) * 32;
      gl_lds16(gA0 + ko, lA0); gl_lds16(gA1 + ko, lA0 + 512);
      gl_lds16(gB0 + ko, lB0); gl_lds16(gB1 + ko, lB0 + 512);
    }
    compute(A1l, B1l);
    __syncthreads();
  }

  float* pbase = part + ((size_t)slot * 4 + kc) * MC * 256;
  #pragma unroll
  for (int mt = 0; mt < 4; ++mt)
    #pragma unroll
    for (int nt = 0; nt < 4; ++nt) {
      const int n_l = wn + nt * 16 + r_fr;
      const int m_l = wm + mt * 16 + quad * 4;
      #pragma unroll
      for (int r = 0; r < 4; ++r)
        pbase[(size_t)(m0 + m_l + r) * 256 + n0 + n_l] = acc[mt][nt][r];
    }
}

// ================= combine partials, normalize, + fp32 residual -> output =======
__global__ __launch_bounds__(256) void combine_kernel(
    const float* __restrict__ part, const float* __restrict__ pk, const float* __restrict__ pv,
    const int* __restrict__ rpos, const float* __restrict__ nrmp,
    const float* __restrict__ sums_g, float* __restrict__ out, int bh0)
{
  const int slot = blockIdx.y;
  const int m = blockIdx.x * 4 + (threadIdx.x >> 6);
  const int lane = threadIdx.x & 63;
  const int bh = bh0 + slot;
  const float nrm = nrmp[0];
  const float rw = 1.0f - nrm;
  const float scale = nrm / sums_g[slot * MC + m];     // softmax normalization
  const int pos = rpos[slot * MC + m];
  const float* krow = pk + ((size_t)bh * S + pos) * DD;
  const float* vrow = pv + ((size_t)bh * S + pos) * DD;
  const size_t pb = (size_t)slot * 4 * MC * 256;
  #pragma unroll
  for (int h = 0; h < 2; ++h) {
    const int d = lane + h * 64;
    float sk = 0.0f, sv = 0.0f;
    #pragma unroll
    for (int kcc = 0; kcc < 4; ++kcc) {
      const float* pp = part + pb + (size_t)kcc * MC * 256 + (size_t)m * 256;
      sk += pp[d];
      sv += pp[128 + d];
    }
    sk = sk * scale + rw * krow[d];
    sv = sv * scale + rw * vrow[d];
    out[((size_t)bh * 512 + KEEP + m) * DD + d] = sk;
    out[KEYS_TOTAL + ((size_t)bh * 512 + KEEP + m) * DD + d] = sv;
  }
}

// =============================== launch =========================================
extern "C" void kernel_launch(void* const* d_in, const int* in_sizes, int n_in,
                              void* d_out, int out_size, void* d_ws, size_t ws_size,
                              hipStream_t stream)
{
  (void)in_sizes; (void)n_in; (void)out_size;
  const float* pk = (const float*)d_in[0];
  const float* pv = (const float*)d_in[1];
  const float* scores = (const float*)d_in[2];
  const float* w0 = (const float*)d_in[3];
  const float* b0 = (const float*)d_in[4];
  const float* w1 = (const float*)d_in[5];
  const float* b1 = (const float*)d_in[6];
  const float* nrmp = (const float*)d_in[7];
  float* out = (float*)d_out;
  char* ws = (char*)d_ws;

  auto alignup = [](size_t x) { return (x + 255) & ~(size_t)255; };
  const size_t offA0 = 0;
  const size_t offA1 = alignup(offA0 + (size_t)OC0 * KK0 * 2);
  const size_t fixed_end = alignup(offA1 + (size_t)OC1 * KK1 * 2);

  const size_t sz_np = (size_t)SP * 4;
  const size_t sz_hh = (size_t)KEEP * 4;
  const size_t sz_rp = (size_t)MC * 4;
  const size_t sz_sm = (size_t)MC * 4;
  const size_t sz_xtm = (size_t)(SP + 2) * 256 * 2;
  const size_t sz_xdm = (size_t)256 * SP * 2;
  const size_t sz_y0 = (size_t)(SP + 2) * 512 * 2;
  const size_t sz_w = (size_t)MC * SP * 2;
  const size_t sz_part = (size_t)4 * MC * 256 * 4;

  auto need_for = [&](int g) -> size_t {
    size_t o = fixed_end;
    o = alignup(o + (size_t)g * sz_np);
    o = alignup(o + (size_t)g * sz_hh);
    o = alignup(o + (size_t)g * sz_rp);
    o = alignup(o + (size_t)g * sz_sm);
    o = alignup(o + (size_t)g * sz_xtm);
    o = alignup(o + (size_t)g * sz_xdm);
    o = alignup(o + (size_t)g * sz_y0);
    o = alignup(o + (size_t)g * sz_w);
    o = alignup(o + (size_t)g * sz_part);
    return o;
  };
  // adaptive bh-chunking so scratch fits whatever ws_size we were given
  int G = 1;
  const int cand[7] = {64, 32, 16, 8, 4, 2, 1};
  for (int ci = 0; ci < 7; ++ci) { if (need_for(cand[ci]) <= ws_size) { G = cand[ci]; break; } }

  size_t o = fixed_end;
  const size_t off_np = o;  o = alignup(o + (size_t)G * sz_np);
  const size_t off_hh = o;  o = alignup(o + (size_t)G * sz_hh);
  const size_t off_rp = o;  o = alignup(o + (size_t)G * sz_rp);
  const size_t off_sm = o;  o = alignup(o + (size_t)G * sz_sm);
  const size_t off_xtm = o; o = alignup(o + (size_t)G * sz_xtm);
  const size_t off_xdm = o; o = alignup(o + (size_t)G * sz_xdm);
  const size_t off_y0 = o;  o = alignup(o + (size_t)G * sz_y0);
  const size_t off_w = o;   o = alignup(o + (size_t)G * sz_w);
  const size_t off_part = o;

  u16* A0 = (u16*)(ws + offA0);
  u16* A1 = (u16*)(ws + offA1);
  int* np_p = (int*)(ws + off_np);
  int* hh_p = (int*)(ws + off_hh);
  int* rp_p = (int*)(ws + off_rp);
  float* sums = (float*)(ws + off_sm);
  u16* Xtm = (u16*)(ws + off_xtm);
  u16* Xdm = (u16*)(ws + off_xdm);
  u16* Y0 = (u16*)(ws + off_y0);
  u16* Wmm = (u16*)(ws + off_w);
  float* part = (float*)(ws + off_part);

  prepack_kernel<<<1536, 256, 0, stream>>>(w0, w1, A0, A1);

  for (int bh0 = 0; bh0 < NBH; bh0 += G) {
    sel_kernel<<<G, 256, 0, stream>>>(scores, bh0, np_p, hh_p, rp_p, sums);
    gather_kernel<<<dim3(124, G), 256, 0, stream>>>(pk, pv, np_p, Xtm, Xdm, Y0, bh0);
    hhgather_kernel<<<dim3(16, G), 256, 0, stream>>>(pk, pv, hh_p, out, bh0);
    conv_gemm_kernel<OC0, KK0, 256, 0><<<dim3(248, G), 256, 0, stream>>>(A0, Xtm, b0, Y0, sums);
    conv_gemm_kernel<OC1, KK1, 512, 1><<<dim3(124, G), 256, 0, stream>>>(A1, Y0, b1, Wmm, sums);
    gemm3_kernel<<<dim3(4, 4, G), 256, 0, stream>>>(Wmm, Xdm, part);
    combine_kernel<<<dim3(64, G), 256, 0, stream>>>(part, pk, pv, rp_p, nrmp, sums, out, bh0);
  }
}

// Round 3
// 2365.496 us; speedup vs baseline: 1.0487x; 1.0487x over previous
//
#include <hip/hip_runtime.h>
#include <stdint.h>

// ---------------- problem constants ----------------
#define BB 2
#define HH 32
#define NBH 64          // BB*HH
#define S 8192
#define DD 128
#define SP 7936         // S - KEEP
#define MC 256          // MEM_COMPRESS
#define KEEP 256
#define LOC 64
#define KTOP 192        // KEEP - LOC
#define N1 8128         // S - LOC (top-k domain)
#define OC0 512
#define IC0 256
#define KK0 768         // 3*IC0 (im2col K)
#define OC1 256
#define IC1 512
#define KK1 1536
#define KEYS_TOTAL ((size_t)NBH * 512 * DD)   // 4,194,304

typedef unsigned short u16;
typedef __attribute__((ext_vector_type(2))) unsigned short us2;
typedef __attribute__((ext_vector_type(4))) unsigned short us4;
typedef __attribute__((ext_vector_type(8))) unsigned short us8;
typedef __attribute__((ext_vector_type(8))) short bfrag;   // 8 bf16 (4 VGPRs) MFMA input
typedef __attribute__((ext_vector_type(4))) float ffrag;   // 4 fp32 MFMA acc

__device__ __forceinline__ u16 f2bf(float x) {          // RNE fp32->bf16
  uint32_t u = __float_as_uint(x);
  return (u16)((u + 0x7FFFu + ((u >> 16) & 1u)) >> 16);
}
__device__ __forceinline__ float bf2f(u16 h) {
  return __uint_as_float(((uint32_t)h) << 16);
}

// async global->LDS, 16 B per lane. LDS dest is wave-uniform base + lane*16;
// global source is per-lane.  [m97 recipe: width=16 -> global_load_lds_dwordx4]
__device__ __forceinline__ void gl_lds16(const u16* g, u16* l) {
  __builtin_amdgcn_global_load_lds(
      (const __attribute__((address_space(1))) void*)g,
      (__attribute__((address_space(3))) void*)l,
      16, 0, 0);
}

// ================= selection (exact top-k, tie -> lower index) =================
// Also zero-inits the per-(slot,row) softmax-denominator buffer for this chunk.
__global__ __launch_bounds__(256) void sel_kernel(
    const float* __restrict__ scores, int bh0,
    int* __restrict__ non_pos_g, int* __restrict__ hh_pos_g, int* __restrict__ rpos_g,
    float* __restrict__ sums_g)
{
  __shared__ uint32_t keys[N1];        // transformed order-preserving bits, 31.75 KB
  __shared__ u16 nonpos_l[SP];         // 15.5 KB
  __shared__ uint32_t hist[256];
  __shared__ int scanb[256];
  __shared__ uint32_t s_pref, s_pmask;
  __shared__ int s_krem;

  const int slot = blockIdx.x;
  const int bh = bh0 + slot;
  const int tid = threadIdx.x;
  const float* row = scores + (size_t)bh * S;

  sums_g[slot * MC + tid] = 0.0f;      // MC == 256 == blockDim

  for (int i = tid; i < N1; i += 256) {
    uint32_t u = __float_as_uint(row[i]);
    keys[i] = (u >> 31) ? ~u : (u | 0x80000000u);   // monotone map, descending order
  }
  __syncthreads();

  // ---- stage 1: 192-th largest over [0, N1)
  if (tid == 0) { s_pref = 0; s_pmask = 0; s_krem = KTOP; }
  __syncthreads();
  for (int shift = 24; shift >= 0; shift -= 8) {
    hist[tid] = 0; __syncthreads();
    uint32_t pm = s_pmask, pf = s_pref;
    for (int i = tid; i < N1; i += 256) {
      uint32_t u = keys[i];
      if ((u & pm) == pf) atomicAdd(&hist[(u >> shift) & 255u], 1u);
    }
    __syncthreads();
    if (tid == 0) {
      int krem = s_krem, c = 0, chosen = 0;
      for (int b = 255; b >= 0; --b) {
        int h = (int)hist[b];
        if (krem <= c + h) { chosen = b; krem -= c; break; }
        c += h;
      }
      s_pref |= ((uint32_t)chosen) << shift;
      s_pmask |= 255u << shift;
      s_krem = krem;
    }
    __syncthreads();
  }
  const uint32_t T1 = s_pref;
  const int need1 = s_krem;          // #elements == T1 to take (ascending index)

  // blocked ownership: 32 indices per thread over [0, S)
  const int base = tid * 32;
  int eqc = 0;
  for (int j = 0; j < 32; ++j) { int i = base + j; if (i < N1 && keys[i] == T1) ++eqc; }
  __syncthreads(); scanb[tid] = eqc; __syncthreads();
  if (tid == 0) { int run = 0; for (int t = 0; t < 256; ++t) { int v = scanb[t]; scanb[t] = run; run += v; } }
  __syncthreads();
  const int eqb = scanb[tid];

  int mcnt = 0;
  { int er = eqb;
    for (int j = 0; j < 32; ++j) {
      int i = base + j; bool m;
      if (i >= N1) m = true;
      else { uint32_t u = keys[i];
        if (u > T1) m = true; else if (u == T1) { m = (er < need1); ++er; } else m = false; }
      if (m) ++mcnt;
    } }
  __syncthreads(); scanb[tid] = mcnt; __syncthreads();
  if (tid == 0) { int run = 0; for (int t = 0; t < 256; ++t) { int v = scanb[t]; scanb[t] = run; run += v; } }
  __syncthreads();
  { int mo = scanb[tid];
    int no = base - mo;              // unmasked-before-base
    int er = eqb;
    for (int j = 0; j < 32; ++j) {
      int i = base + j; bool m;
      if (i >= N1) m = true;
      else { uint32_t u = keys[i];
        if (u > T1) m = true; else if (u == T1) { m = (er < need1); ++er; } else m = false; }
      if (m) { hh_pos_g[slot * KEEP + mo] = i; ++mo; }
      else   { nonpos_l[no] = (u16)i; non_pos_g[(size_t)slot * SP + no] = i; ++no; }
    } }
  __syncthreads();

  // ---- stage 2: 256-th largest over non_scores (7936), same tie rule
  if (tid == 0) { s_pref = 0; s_pmask = 0; s_krem = MC; }
  __syncthreads();
  for (int shift = 24; shift >= 0; shift -= 8) {
    hist[tid] = 0; __syncthreads();
    uint32_t pm = s_pmask, pf = s_pref;
    for (int i = tid; i < SP; i += 256) {
      uint32_t u = keys[nonpos_l[i]];
      if ((u & pm) == pf) atomicAdd(&hist[(u >> shift) & 255u], 1u);
    }
    __syncthreads();
    if (tid == 0) {
      int krem = s_krem, c = 0, chosen = 0;
      for (int b = 255; b >= 0; --b) {
        int h = (int)hist[b];
        if (krem <= c + h) { chosen = b; krem -= c; break; }
        c += h;
      }
      s_pref |= ((uint32_t)chosen) << shift;
      s_pmask |= 255u << shift;
      s_krem = krem;
    }
    __syncthreads();
  }
  const uint32_t T2 = s_pref;
  const int need2 = s_krem;
  const int b2 = tid * 31;           // 256*31 == 7936 exactly
  int eqc2 = 0;
  for (int j = 0; j < 31; ++j) { if (keys[nonpos_l[b2 + j]] == T2) ++eqc2; }
  __syncthreads(); scanb[tid] = eqc2; __syncthreads();
  if (tid == 0) { int run = 0; for (int t = 0; t < 256; ++t) { int v = scanb[t]; scanb[t] = run; run += v; } }
  __syncthreads();
  const int eqb2 = scanb[tid];
  int sc = 0;
  { int er = eqb2;
    for (int j = 0; j < 31; ++j) {
      uint32_t u = keys[nonpos_l[b2 + j]]; bool sel;
      if (u > T2) sel = true; else if (u == T2) { sel = (er < need2); ++er; } else sel = false;
      if (sel) ++sc;
    } }
  __syncthreads(); scanb[tid] = sc; __syncthreads();
  if (tid == 0) { int run = 0; for (int t = 0; t < 256; ++t) { int v = scanb[t]; scanb[t] = run; run += v; } }
  __syncthreads();
  { int so = scanb[tid];
    int er = eqb2;
    for (int j = 0; j < 31; ++j) {
      int i = b2 + j; uint32_t u = keys[nonpos_l[i]]; bool sel;
      if (u > T2) sel = true; else if (u == T2) { sel = (er < need2); ++er; } else sel = false;
      if (sel) { rpos_g[slot * MC + so] = (int)nonpos_l[i]; ++so; }   // ORIGINAL position
    } }
}

// ================= gather non-positions into bf16 X (time-major + d-major) ======
__global__ __launch_bounds__(256) void gather_kernel(
    const float* __restrict__ pk, const float* __restrict__ pv,
    const int* __restrict__ non_pos, u16* __restrict__ Xtm_all,
    u16* __restrict__ Xdm_all, u16* __restrict__ Y0_all, int bh0)
{
  __shared__ u16 lt[256][66];        // [ch][t_local], +2 pad vs bank conflicts
  const int slot = blockIdx.y, tile = blockIdx.x;
  const int bh = bh0 + slot;
  const int tid = threadIdx.x, lane = tid & 63, q = tid >> 6;
  const int t0 = tile * 64;
  u16* Xtm = Xtm_all + (size_t)slot * (SP + 2) * 256 + 256;   // logical row 0
  const int* np = non_pos + (size_t)slot * SP;

  for (int r = q; r < 64; r += 4) {
    const int t = t0 + r;
    const int pos = np[t];
    float2 kk = ((const float2*)(pk + ((size_t)bh * S + pos) * DD))[lane];
    float2 vv = ((const float2*)(pv + ((size_t)bh * S + pos) * DD))[lane];
    u16 k0 = f2bf(kk.x), k1 = f2bf(kk.y), v0 = f2bf(vv.x), v1 = f2bf(vv.y);
    us2 tk = {k0, k1}; us2 tv = {v0, v1};
    *(us2*)&Xtm[(size_t)t * 256 + lane * 2] = tk;
    *(us2*)&Xtm[(size_t)t * 256 + 128 + lane * 2] = tv;
    lt[lane * 2][r] = k0; lt[lane * 2 + 1][r] = k1;
    lt[128 + lane * 2][r] = v0; lt[128 + lane * 2 + 1][r] = v1;
  }
  // zero pad rows (conv tap t=-1 / t=SP), Y0 pads too
  if (tile == 0) {
    Xtm[-256 + tid] = 0;
    u16* y0 = Y0_all + (size_t)slot * (SP + 2) * 512;
    y0[tid] = 0; y0[tid + 256] = 0;
  } else if (tile == 123) {
    Xtm[(size_t)SP * 256 + tid] = 0;
    u16* y0 = Y0_all + (size_t)slot * (SP + 2) * 512 + (size_t)(SP + 1) * 512;
    y0[tid] = 0; y0[tid + 256] = 0;
  }
  __syncthreads();
  // X_dm rows (d-major, for weighting-GEMM B^T) — coalesced: 16 consecutive
  // lanes cover one row's 128 B (uint2 = 4 bf16 each) -> 4x128B tx per wave-store.
  u16* Xdm = Xdm_all + (size_t)slot * 256 * SP;
  for (int idx = tid; idx < 4096; idx += 256) {
    const int r = idx >> 4, j = idx & 15;
    uint2 v = *(const uint2*)&lt[r][j * 4];
    *(uint2*)(Xdm + (size_t)r * SP + t0 + j * 4) = v;
  }
}

// ================= heavy-hitter gather straight to output (fp32, exact) ========
__global__ __launch_bounds__(256) void hhgather_kernel(
    const float* __restrict__ pk, const float* __restrict__ pv,
    const int* __restrict__ hh_pos, float* __restrict__ out, int bh0)
{
  const int slot = blockIdx.y, bh = bh0 + slot;
  const int tid = threadIdx.x, lane = tid & 63, q = tid >> 6;
  const int r0 = blockIdx.x * 16;
  const int* hp = hh_pos + slot * KEEP;
  for (int r = r0 + q; r < r0 + 16; r += 4) {
    const int pos = hp[r];
    float2 kk = ((const float2*)(pk + ((size_t)bh * S + pos) * DD))[lane];
    float2 vv = ((const float2*)(pv + ((size_t)bh * S + pos) * DD))[lane];
    ((float2*)(out + ((size_t)bh * 512 + r) * DD))[lane] = kk;
    ((float2*)(out + KEYS_TOTAL + ((size_t)bh * 512 + r) * DD))[lane] = vv;
  }
}

// ================= weight prepack (im2col m-major, bf16) ========================
__global__ __launch_bounds__(256) void prepack_kernel(
    const float* __restrict__ w0, const float* __restrict__ w1,
    u16* __restrict__ A0, u16* __restrict__ A1)
{
  const int idx = blockIdx.x * 256 + threadIdx.x;
  if (idx < OC0 * KK0) {
    int oc = idx / KK0, r = idx % KK0, tau = r / IC0, ic = r % IC0;
    A0[idx] = f2bf(w0[(oc * IC0 + ic) * 3 + tau]);
  }
  if (idx < OC1 * KK1) {
    int oc = idx / KK1, r = idx % KK1, tau = r / IC1, ic = r % IC1;
    A1[idx] = f2bf(w1[(oc * IC1 + ic) * 3 + tau]);
  }
}

// ================= conv-as-GEMM (im2col via shifted time-major B) ===============
// C[oc][t] = sum_tau sum_ic W[oc][tau*TAUCH+ic] * Bsrc[t+tau-1][ic], then +bias, silu.
// Staging: async global_load_lds width=16, SINGLE-buffered (round-1 proven loop)
// but BK=64: two 32-wide K sub-tiles staged per barrier pair, stored as separate
// [128][32] LDS sub-tiles (same 64-B row stride -> same bank behavior as BK=32),
// then both MFMA passes run back-to-back. Halves the vmcnt(0)-drain barriers and
// amortizes each exposed load latency over 32 MFMAs.
// Grid is 1-D over (t,m) with m FASTEST + bijective XCD-chunk remap (m204) so
// the m-tiles sharing a B panel land on the same XCD's L2 (FETCH 781->345 MB
// measured in round 2 — kept).
// OUTMODE 0: store silu(x) time-major (Y0, pad rows at -1/SP)
// OUTMODE 1: store p = exp(silu(x)) m-major (unnormalized softmax numerator)
//            and atomically accumulate per-row sums (softmax denominator).
template<int MTOT, int KTOT, int TAUCH, int OUTMODE>
__global__ __launch_bounds__(256) void conv_gemm_kernel(
    const u16* __restrict__ Apack, const u16* __restrict__ Bsrc_all,
    const float* __restrict__ bias, u16* __restrict__ out_all,
    float* __restrict__ sums_g)
{
  constexpr int MTILES = MTOT / 128;
  constexpr int NK = KTOT / 64;          // 12 (conv0) / 24 (conv1)
  constexpr int NX = (SP / 128) * MTILES;
  constexpr int QX = NX / 8, RX = NX % 8;
  __shared__ u16 smem[128 * 136];    // staging A[0:8192) B[8192:16384); epilogue whole
  __shared__ float rowsum[128];
  u16* Asl = smem;                   // sub-tile kk at Asl + kk*4096, [128][32]
  u16* Bsl = smem + 8192;
  const int slot = blockIdx.y;
  // XCD-chunked bijective swizzle, m-fastest within chunk
  const int lin = blockIdx.x;
  const int xcd = lin & 7, pos = lin >> 3;
  const int widx = (xcd < RX ? xcd * (QX + 1) : RX * (QX + 1) + (xcd - RX) * QX) + pos;
  const int m0 = (widx % MTILES) * 128;
  const int t0 = (widx / MTILES) * 128;
  const int tid = threadIdx.x;
  const int lane = tid & 63, wave = tid >> 6;
  const int wm = (wave & 1) * 64, wn = (wave >> 1) * 64;
  const int r_fr = lane & 15, quad = lane >> 4;
  const u16* Bsrc = Bsrc_all + (size_t)slot * (size_t)(SP + 2) * TAUCH + TAUCH; // logical row 0

  ffrag acc[4][4];
  #pragma unroll
  for (int a = 0; a < 4; ++a)
    #pragma unroll
    for (int b = 0; b < 4; ++b) acc[a][b] = (ffrag)0.0f;

  // staging: wave w owns rows [32w, 32w+32) of each sub-tile; chunk = 16 rows
  // = 1024 B LDS. Lane l covers row chunk*16 + (l>>2), k-bytes [(l&3)*16, +16).
  const int lrow = lane >> 2, lcol = (lane & 3) * 8;
  const u16* gA = Apack + (size_t)(m0 + wave * 32 + lrow) * KTOT + lcol;
  const u16* gB = Bsrc + ((long)t0 + wave * 32 + lrow - 1) * (long)TAUCH + lcol;
  u16* lA = Asl + wave * 1024;                   // wave-uniform LDS bases
  u16* lB = Bsl + wave * 1024;

  for (int kt = 0; kt < NK; ++kt) {
    const int ko = kt * 64;
    __syncthreads();                 // prev step's frag reads done before overwrite
    gl_lds16(gA + ko,                  lA);              // kk=0, chunk 0
    gl_lds16(gA + ko + 16 * KTOT,      lA + 512);        // kk=0, chunk 1
    gl_lds16(gA + ko + 32,             lA + 4096);       // kk=1, chunk 0
    gl_lds16(gA + ko + 32 + 16 * KTOT, lA + 4096 + 512); // kk=1, chunk 1
    gl_lds16(gB + ko,                  lB);
    gl_lds16(gB + ko + 16 * TAUCH,     lB + 512);
    gl_lds16(gB + ko + 32,             lB + 4096);
    gl_lds16(gB + ko + 32 + 16 * TAUCH, lB + 4096 + 512);
    __syncthreads();                 // drains vmcnt(0): staged data visible
    #pragma unroll
    for (int kk = 0; kk < 2; ++kk) {
      bfrag af[4], bf[4];
      #pragma unroll
      for (int mt = 0; mt < 4; ++mt)
        af[mt] = *(const bfrag*)&Asl[kk * 4096 + (wm + mt * 16 + r_fr) * 32 + quad * 8];
      #pragma unroll
      for (int nt = 0; nt < 4; ++nt)
        bf[nt] = *(const bfrag*)&Bsl[kk * 4096 + (wn + nt * 16 + r_fr) * 32 + quad * 8];
      #pragma unroll
      for (int mt = 0; mt < 4; ++mt)
        #pragma unroll
        for (int nt = 0; nt < 4; ++nt)
          acc[mt][nt] = __builtin_amdgcn_mfma_f32_16x16x32_bf16(af[mt], bf[nt], acc[mt][nt], 0, 0, 0);
    }
  }
  __syncthreads();
  if constexpr (OUTMODE == 1) {
    if (tid < 128) rowsum[tid] = 0.0f;
    __syncthreads();
  }

  // epilogue: bias + silu (+exp for mode 1) -> bf16 -> LDS (for coalesced stores)
  #pragma unroll
  for (int mt = 0; mt < 4; ++mt) {
    float srow4[4] = {0.0f, 0.0f, 0.0f, 0.0f};
    #pragma unroll
    for (int nt = 0; nt < 4; ++nt) {
      const int n_l = wn + nt * 16 + r_fr;
      const int m_l = wm + mt * 16 + quad * 4;
      if constexpr (OUTMODE == 0) {
        u16 h4[4];
        #pragma unroll
        for (int r = 0; r < 4; ++r) {
          float x = acc[mt][nt][r] + bias[m0 + m_l + r];
          float y = x / (1.0f + __expf(-x));
          h4[r] = f2bf(y);
        }
        us4 p = {h4[0], h4[1], h4[2], h4[3]};
        *(us4*)&smem[n_l * 136 + m_l] = p;             // trans[n][m]
      } else {
        #pragma unroll
        for (int r = 0; r < 4; ++r) {
          float x = acc[mt][nt][r] + bias[m0 + m_l + r];
          float y = x / (1.0f + __expf(-x));
          float p = __expf(fminf(y, 60.0f));           // no-max-sub softmax numerator
          srow4[r] += p;
          smem[(m_l + r) * 136 + n_l] = f2bf(p);       // trans[m][n]
        }
      }
    }
    if constexpr (OUTMODE == 1) {
      #pragma unroll
      for (int r = 0; r < 4; ++r) {
        float s = srow4[r];
        s += __shfl_xor(s, 1, 64);
        s += __shfl_xor(s, 2, 64);
        s += __shfl_xor(s, 4, 64);
        s += __shfl_xor(s, 8, 64);
        if ((lane & 15) == 0)
          atomicAdd(&rowsum[wm + mt * 16 + quad * 4 + r], s);
      }
    }
  }
  __syncthreads();
  if constexpr (OUTMODE == 1) {
    if (tid < 128) atomicAdd(&sums_g[slot * MC + m0 + tid], rowsum[tid]);
  }
  const int rr = tid >> 1, half = tid & 1;
  if (OUTMODE == 0) {
    u16* orow = out_all + (size_t)slot * (size_t)(SP + 2) * MTOT + MTOT
              + (size_t)(t0 + rr) * MTOT + m0 + half * 64;
    const u16* srcr = &smem[rr * 136 + half * 64];
    #pragma unroll
    for (int j = 0; j < 8; ++j) *(us8*)(orow + j * 8) = *(const us8*)(srcr + j * 8);
  } else {
    u16* orow = out_all + (size_t)slot * (size_t)MC * SP
              + (size_t)(m0 + rr) * SP + t0 + half * 64;
    const u16* srcr = &smem[rr * 136 + half * 64];
    #pragma unroll
    for (int j = 0; j < 8; ++j) *(us8*)(orow + j * 8) = *(const us8*)(srcr + j * 8);
  }
}

// ================= weighting GEMM: C(256m x 256d) = P(256xSP) x non(SPx256) =====
// A = unnormalized p (bf16, m-major); B^T = Xdm (256 d-rows x SP).
// K split 4 ways into fp32 partials (normalization applied in combine).
// Staging: async global_load_lds width=16, single-buffered, BK=64 (same as conv).
__global__ __launch_bounds__(256) void gemm3_kernel(
    const u16* __restrict__ Wmm_all, const u16* __restrict__ Xdm_all,
    float* __restrict__ part)
{
  __shared__ u16 smem[16384];          // A[0:8192) B[8192:16384), 2 sub-tiles each
  u16* Asl = smem;
  u16* Bsl = smem + 8192;
  const int kc = blockIdx.x;            // 0..3
  const int tile = blockIdx.y;          // 0..3  (2m x 2n)
  const int slot = blockIdx.z;
  const int m0 = (tile >> 1) * 128, n0 = (tile & 1) * 128;
  const int tid = threadIdx.x;
  const int lane = tid & 63, wave = tid >> 6;
  const int wm = (wave & 1) * 64, wn = (wave >> 1) * 64;
  const int r_fr = lane & 15, quad = lane >> 4;
  const u16* A = Wmm_all + (size_t)slot * MC * SP;
  const u16* Bt = Xdm_all + (size_t)slot * 256 * SP;
  const int kbeg = kc * (SP / 4);
  constexpr int NK = (SP / 4) / 64;     // 31

  ffrag acc[4][4];
  #pragma unroll
  for (int a = 0; a < 4; ++a)
    #pragma unroll
    for (int b = 0; b < 4; ++b) acc[a][b] = (ffrag)0.0f;

  const int lrow = lane >> 2, lcol = (lane & 3) * 8;
  const u16* gA = A + (size_t)(m0 + wave * 32 + lrow) * SP + kbeg + lcol;
  const u16* gB = Bt + (size_t)(n0 + wave * 32 + lrow) * SP + kbeg + lcol;
  u16* lA = Asl + wave * 1024;
  u16* lB = Bsl + wave * 1024;

  for (int kt = 0; kt < NK; ++kt) {
    const int ko = kt * 64;
    __syncthreads();
    gl_lds16(gA + ko,                lA);
    gl_lds16(gA + ko + 16 * SP,      lA + 512);
    gl_lds16(gA + ko + 32,           lA + 4096);
    gl_lds16(gA + ko + 32 + 16 * SP, lA + 4096 + 512);
    gl_lds16(gB + ko,                lB);
    gl_lds16(gB + ko + 16 * SP,      lB + 512);
    gl_lds16(gB + ko + 32,           lB + 4096);
    gl_lds16(gB + ko + 32 + 16 * SP, lB + 4096 + 512);
    __syncthreads();
    #pragma unroll
    for (int kk = 0; kk < 2; ++kk) {
      bfrag af[4], bf[4];
      #pragma unroll
      for (int mt = 0; mt < 4; ++mt)
        af[mt] = *(const bfrag*)&Asl[kk * 4096 + (wm + mt * 16 + r_fr) * 32 + quad * 8];
      #pragma unroll
      for (int nt = 0; nt < 4; ++nt)
        bf[nt] = *(const bfrag*)&Bsl[kk * 4096 + (wn + nt * 16 + r_fr) * 32 + quad * 8];
      #pragma unroll
      for (int mt = 0; mt < 4; ++mt)
        #pragma unroll
        for (int nt = 0; nt < 4; ++nt)
          acc[mt][nt] = __builtin_amdgcn_mfma_f32_16x16x32_bf16(af[mt], bf[nt], acc[mt][nt], 0, 0, 0);
    }
  }

  float* pbase = part + ((size_t)slot * 4 + kc) * MC * 256;
  #pragma unroll
  for (int mt = 0; mt < 4; ++mt)
    #pragma unroll
    for (int nt = 0; nt < 4; ++nt) {
      const int n_l = wn + nt * 16 + r_fr;
      const int m_l = wm + mt * 16 + quad * 4;
      #pragma unroll
      for (int r = 0; r < 4; ++r)
        pbase[(size_t)(m0 + m_l + r) * 256 + n0 + n_l] = acc[mt][nt][r];
    }
}

// ================= combine partials, normalize, + fp32 residual -> output =======
__global__ __launch_bounds__(256) void combine_kernel(
    const float* __restrict__ part, const float* __restrict__ pk, const float* __restrict__ pv,
    const int* __restrict__ rpos, const float* __restrict__ nrmp,
    const float* __restrict__ sums_g, float* __restrict__ out, int bh0)
{
  const int slot = blockIdx.y;
  const int m = blockIdx.x * 4 + (threadIdx.x >> 6);
  const int lane = threadIdx.x & 63;
  const int bh = bh0 + slot;
  const float nrm = nrmp[0];
  const float rw = 1.0f - nrm;
  const float scale = nrm / sums_g[slot * MC + m];     // softmax normalization
  const int pos = rpos[slot * MC + m];
  const float* krow = pk + ((size_t)bh * S + pos) * DD;
  const float* vrow = pv + ((size_t)bh * S + pos) * DD;
  const size_t pb = (size_t)slot * 4 * MC * 256;
  #pragma unroll
  for (int h = 0; h < 2; ++h) {
    const int d = lane + h * 64;
    float sk = 0.0f, sv = 0.0f;
    #pragma unroll
    for (int kcc = 0; kcc < 4; ++kcc) {
      const float* pp = part + pb + (size_t)kcc * MC * 256 + (size_t)m * 256;
      sk += pp[d];
      sv += pp[128 + d];
    }
    sk = sk * scale + rw * krow[d];
    sv = sv * scale + rw * vrow[d];
    out[((size_t)bh * 512 + KEEP + m) * DD + d] = sk;
    out[KEYS_TOTAL + ((size_t)bh * 512 + KEEP + m) * DD + d] = sv;
  }
}

// =============================== launch =========================================
extern "C" void kernel_launch(void* const* d_in, const int* in_sizes, int n_in,
                              void* d_out, int out_size, void* d_ws, size_t ws_size,
                              hipStream_t stream)
{
  (void)in_sizes; (void)n_in; (void)out_size;
  const float* pk = (const float*)d_in[0];
  const float* pv = (const float*)d_in[1];
  const float* scores = (const float*)d_in[2];
  const float* w0 = (const float*)d_in[3];
  const float* b0 = (const float*)d_in[4];
  const float* w1 = (const float*)d_in[5];
  const float* b1 = (const float*)d_in[6];
  const float* nrmp = (const float*)d_in[7];
  float* out = (float*)d_out;
  char* ws = (char*)d_ws;

  auto alignup = [](size_t x) { return (x + 255) & ~(size_t)255; };
  const size_t offA0 = 0;
  const size_t offA1 = alignup(offA0 + (size_t)OC0 * KK0 * 2);
  const size_t fixed_end = alignup(offA1 + (size_t)OC1 * KK1 * 2);

  const size_t sz_np = (size_t)SP * 4;
  const size_t sz_hh = (size_t)KEEP * 4;
  const size_t sz_rp = (size_t)MC * 4;
  const size_t sz_sm = (size_t)MC * 4;
  const size_t sz_xtm = (size_t)(SP + 2) * 256 * 2;
  const size_t sz_xdm = (size_t)256 * SP * 2;
  const size_t sz_y0 = (size_t)(SP + 2) * 512 * 2;
  const size_t sz_w = (size_t)MC * SP * 2;
  const size_t sz_part = (size_t)4 * MC * 256 * 4;

  auto need_for = [&](int g) -> size_t {
    size_t o = fixed_end;
    o = alignup(o + (size_t)g * sz_np);
    o = alignup(o + (size_t)g * sz_hh);
    o = alignup(o + (size_t)g * sz_rp);
    o = alignup(o + (size_t)g * sz_sm);
    o = alignup(o + (size_t)g * sz_xtm);
    o = alignup(o + (size_t)g * sz_xdm);
    o = alignup(o + (size_t)g * sz_y0);
    o = alignup(o + (size_t)g * sz_w);
    o = alignup(o + (size_t)g * sz_part);
    return o;
  };
  // adaptive bh-chunking so scratch fits whatever ws_size we were given
  int G = 1;
  const int cand[7] = {64, 32, 16, 8, 4, 2, 1};
  for (int ci = 0; ci < 7; ++ci) { if (need_for(cand[ci]) <= ws_size) { G = cand[ci]; break; } }

  size_t o = fixed_end;
  const size_t off_np = o;  o = alignup(o + (size_t)G * sz_np);
  const size_t off_hh = o;  o = alignup(o + (size_t)G * sz_hh);
  const size_t off_rp = o;  o = alignup(o + (size_t)G * sz_rp);
  const size_t off_sm = o;  o = alignup(o + (size_t)G * sz_sm);
  const size_t off_xtm = o; o = alignup(o + (size_t)G * sz_xtm);
  const size_t off_xdm = o; o = alignup(o + (size_t)G * sz_xdm);
  const size_t off_y0 = o;  o = alignup(o + (size_t)G * sz_y0);
  const size_t off_w = o;   o = alignup(o + (size_t)G * sz_w);
  const size_t off_part = o;

  u16* A0 = (u16*)(ws + offA0);
  u16* A1 = (u16*)(ws + offA1);
  int* np_p = (int*)(ws + off_np);
  int* hh_p = (int*)(ws + off_hh);
  int* rp_p = (int*)(ws + off_rp);
  float* sums = (float*)(ws + off_sm);
  u16* Xtm = (u16*)(ws + off_xtm);
  u16* Xdm = (u16*)(ws + off_xdm);
  u16* Y0 = (u16*)(ws + off_y0);
  u16* Wmm = (u16*)(ws + off_w);
  float* part = (float*)(ws + off_part);

  prepack_kernel<<<1536, 256, 0, stream>>>(w0, w1, A0, A1);

  for (int bh0 = 0; bh0 < NBH; bh0 += G) {
    sel_kernel<<<G, 256, 0, stream>>>(scores, bh0, np_p, hh_p, rp_p, sums);
    gather_kernel<<<dim3(124, G), 256, 0, stream>>>(pk, pv, np_p, Xtm, Xdm, Y0, bh0);
    hhgather_kernel<<<dim3(16, G), 256, 0, stream>>>(pk, pv, hh_p, out, bh0);
    conv_gemm_kernel<OC0, KK0, 256, 0><<<dim3(248, G), 256, 0, stream>>>(A0, Xtm, b0, Y0, sums);
    conv_gemm_kernel<OC1, KK1, 512, 1><<<dim3(124, G), 256, 0, stream>>>(A1, Y0, b1, Wmm, sums);
    gemm3_kernel<<<dim3(4, 4, G), 256, 0, stream>>>(Wmm, Xdm, part);
    combine_kernel<<<dim3(64, G), 256, 0, stream>>>(part, pk, pv, rp_p, nrmp, sums, out, bh0);
  }
}